// Round 3
// baseline (620.416 us; speedup 1.0000x reference)
//
#include <hip/hip_runtime.h>
#include <cmath>

#define NMEM 65536
#define MSZ  256
#define EPSC 1e-8f

// ---- workspace layout (float offsets) ----
enum : int {
    OFF_GATES = 0,        // 4096
    OFF_CTRL  = 4096,     // 1024
    OFF_OW    = 5120,     // 4*774 = 3096
    OFF_ORR   = 8216,     // 4*262 = 1048
    OFF_K     = 9264,     // 8*256 (tanh keys; p=0..3 write heads, 4..7 read heads)
    OFF_E     = 11312,    // 4*256 sigmoid erase
    OFF_A     = 12336,    // 4*256 tanh add
    OFF_SCAL  = 13360,    // 8*8: [knorm, beta, g, s0, s1, s2, gamma, -]
    OFF_READS = 13424,    // 4*256 (atomic accumulated)
    OFF_PAIRS = 14448,    // 2048*2 online-softmax partials
    OFF_TPART = 18544,    // 64 sharpen-sum partials
    OFF_SIM   = 18608,    // 65536
    OFF_WSH   = 84144,    // 65536
    WS_FLOATS = 149680
};

__device__ __forceinline__ float wave_sum(float v) {
#pragma unroll
    for (int off = 32; off > 0; off >>= 1) v += __shfl_xor(v, off);
    return v;
}
__device__ __forceinline__ float sigmoidf_(float x) { return 1.f / (1.f + expf(-x)); }
__device__ __forceinline__ float softplusf_(float x) { return (x > 20.f) ? x : log1pf(expf(x)); }
// online softmax helpers: (m, s) = running max and sum of exp(z-m)
__device__ __forceinline__ void online_add(float z, float& m, float& s) {
    if (z > m) { s = s * expf(m - z) + 1.f; m = z; }
    else       { s += expf(z - m); }
}
__device__ __forceinline__ void pair_merge(float& m, float& s, float m2, float s2) {
    if (m2 > m) { s = s * expf(m - m2) + s2; m = m2; }
    else        { s += s2 * expf(m2 - m); }
}

// ---- zero the read accumulators (ws is poisoned each launch) ----
__global__ void k_init(float* __restrict__ ws) {
    int i = blockIdx.x * blockDim.x + threadIdx.x;
    if (i < 1024) ws[OFF_READS + i] = 0.f;
}

// ---- LSTM gates: one wave per output row (4096 rows) ----
__global__ __launch_bounds__(256) void k_gates(
    const float* __restrict__ x, const float* __restrict__ prev_reads,
    const float* __restrict__ prev_h, const float* __restrict__ W_ih,
    const float* __restrict__ W_hh, const float* __restrict__ b_lstm,
    float* __restrict__ ws)
{
    const int row  = (blockIdx.x * 256 + threadIdx.x) >> 6;  // 0..4095
    const int lane = threadIdx.x & 63;
    const float* wrow = W_ih + (size_t)row * 3072;
    float acc = 0.f;
#pragma unroll
    for (int j = lane * 4; j < 3072; j += 256) {
        float4 w4 = *(const float4*)(wrow + j);
        float4 v4 = (j < 2048) ? *(const float4*)(x + j)
                               : *(const float4*)(prev_reads + (j - 2048));
        acc += w4.x * v4.x + w4.y * v4.y + w4.z * v4.z + w4.w * v4.w;
    }
    const float* hrow = W_hh + (size_t)row * 1024;
#pragma unroll
    for (int j = lane * 4; j < 1024; j += 256) {
        float4 w4 = *(const float4*)(hrow + j);
        float4 v4 = *(const float4*)(prev_h + j);
        acc += w4.x * v4.x + w4.y * v4.y + w4.z * v4.z + w4.w * v4.w;
    }
    acc = wave_sum(acc);
    if (lane == 0) ws[OFF_GATES + row] = acc + b_lstm[row];
}

// ---- LSTM cell state -> ctrl ----
__global__ void k_cell(const float* __restrict__ prev_c, float* __restrict__ ws) {
    const int j = blockIdx.x * blockDim.x + threadIdx.x;
    if (j >= 1024) return;
    const float ig = ws[OFF_GATES + j];
    const float fg = ws[OFF_GATES + 1024 + j];
    const float gg = ws[OFF_GATES + 2048 + j];
    ws[OFF_CTRL + j] = sigmoidf_(fg) * prev_c[j] + sigmoidf_(ig) * tanhf(gg);
}

// ---- head FC outputs: 3096 write rows + 1048 read rows, wave per row ----
__global__ __launch_bounds__(256) void k_headfc(
    const float* __restrict__ Ww, const float* __restrict__ bw,
    const float* __restrict__ Wr, const float* __restrict__ br,
    float* __restrict__ ws)
{
    const int gwv  = (blockIdx.x * 256 + threadIdx.x) >> 6;  // 0..4143
    const int lane = threadIdx.x & 63;
    const float* wrow; float bias; int dst;
    if (gwv < 3096) { wrow = Ww + (size_t)gwv * 1024; bias = bw[gwv]; dst = OFF_OW + gwv; }
    else { const int rr = gwv - 3096; wrow = Wr + (size_t)rr * 1024; bias = br[rr]; dst = OFF_ORR + rr; }
    const float* ctrl = ws + OFF_CTRL;
    float acc = 0.f;
#pragma unroll
    for (int j = lane * 4; j < 1024; j += 256) {
        float4 w4 = *(const float4*)(wrow + j);
        float4 v4 = *(const float4*)(ctrl + j);
        acc += w4.x * v4.x + w4.y * v4.y + w4.z * v4.z + w4.w * v4.w;
    }
    acc = wave_sum(acc);
    if (lane == 0) ws[dst] = acc + bias;
}

// ---- derive per-address params: block p handles address p (0..7) ----
__global__ __launch_bounds__(256) void k_params(float* __restrict__ ws) {
    const int p = blockIdx.x, t = threadIdx.x;
    const float* o = (p < 4) ? (ws + OFF_OW + p * 774) : (ws + OFF_ORR + (p - 4) * 262);
    const float kj = tanhf(o[t]);
    ws[OFF_K + p * 256 + t] = kj;
    float ssq = wave_sum(kj * kj);
    __shared__ float red[4];
    if ((t & 63) == 0) red[t >> 6] = ssq;
    __syncthreads();
    if (t == 0) {
        float* sc = ws + OFF_SCAL + p * 8;
        sc[0] = sqrtf(red[0] + red[1] + red[2] + red[3]);  // |k|
        sc[1] = softplusf_(o[256]);                         // beta
        sc[2] = sigmoidf_(o[257]);                          // g
        const float a0 = o[258], a1 = o[259], a2 = o[260];
        const float mm = fmaxf(a0, fmaxf(a1, a2));
        const float e0 = expf(a0 - mm), e1 = expf(a1 - mm), e2 = expf(a2 - mm);
        const float inv = 1.f / (e0 + e1 + e2);
        sc[3] = e0 * inv; sc[4] = e1 * inv; sc[5] = e2 * inv;
        sc[6] = 1.f + softplusf_(o[261]);                   // gamma
    }
    if (p < 4) {
        ws[OFF_E + p * 256 + t] = sigmoidf_(o[262 + t]);
        ws[OFF_A + p * 256 + t] = tanhf(o[518 + t]);
    }
}

// ---- cosine-sim pass (head0 write address): wave per memory row ----
__global__ __launch_bounds__(256) void k_sim(const float* __restrict__ mem,
                                             float* __restrict__ ws, int p)
{
    const int t = threadIdx.x, lane = t & 63, wid = t >> 6;
    const int gw = blockIdx.x * 4 + wid;
    const float4 k4   = *(const float4*)(ws + OFF_K + p * 256 + lane * 4);
    const float knorm = ws[OFF_SCAL + p * 8 + 0];
    const float beta  = ws[OFF_SCAL + p * 8 + 1];
    float m = -INFINITY, s = 0.f;
    for (int r = 0; r < 8; ++r) {
        const int n = gw * 8 + r;
        const float4 v = *(const float4*)(mem + (size_t)n * MSZ + lane * 4);
        float d = v.x * k4.x + v.y * k4.y + v.z * k4.z + v.w * k4.w;
        float q = v.x * v.x + v.y * v.y + v.z * v.z + v.w * v.w;
        d = wave_sum(d); q = wave_sum(q);
        const float sim = d / (sqrtf(q) * knorm + EPSC);
        if (lane == 0) ws[OFF_SIM + n] = sim;
        online_add(beta * sim, m, s);
    }
    __shared__ float sm[4], ss2[4];
    if (lane == 0) { sm[wid] = m; ss2[wid] = s; }
    __syncthreads();
    if (t == 0) {
        float M = sm[0], S = ss2[0];
        for (int i = 1; i < 4; ++i) pair_merge(M, S, sm[i], ss2[i]);
        ws[OFF_PAIRS + blockIdx.x * 2]     = M;
        ws[OFF_PAIRS + blockIdx.x * 2 + 1] = S;
    }
}

// ---- softmax + interpolate + shift + sharpen -> wsh[], Tpart[] ----
__global__ __launch_bounds__(256) void k_smax(const float* __restrict__ prev_w,
                                              float* __restrict__ ws, int p)
{
    const int t = threadIdx.x;
    float m = -INFINITY, s = 0.f;
    for (int i = t; i < 2048; i += 256)
        pair_merge(m, s, ws[OFF_PAIRS + 2 * i], ws[OFF_PAIRS + 2 * i + 1]);
    __shared__ float sm[256], ss[256];
    sm[t] = m; ss[t] = s;
    __syncthreads();
    for (int str = 128; str > 0; str >>= 1) {
        if (t < str) {
            float mm = sm[t], sss = ss[t];
            pair_merge(mm, sss, sm[t + str], ss[t + str]);
            sm[t] = mm; ss[t] = sss;
        }
        __syncthreads();
    }
    const float M = sm[0], invS = 1.f / ss[0];
    const float* sc = ws + OFF_SCAL + p * 8;
    const float beta = sc[1], g = sc[2], s0 = sc[3], s1 = sc[4], s2 = sc[5], gam = sc[6];
    const float* sim = ws + OFF_SIM;
    float tsum = 0.f;
    const int base = blockIdx.x * 1024;
    for (int kk = 0; kk < 4; ++kk) {
        const int n  = base + kk * 256 + t;
        const int np = (n + 1) & (NMEM - 1);
        const int nm = (n + NMEM - 1) & (NMEM - 1);
        const float wg0 = g * expf(beta * sim[n]  - M) * invS + (1.f - g) * prev_w[n];
        const float wgp = g * expf(beta * sim[np] - M) * invS + (1.f - g) * prev_w[np];
        const float wgm = g * expf(beta * sim[nm] - M) * invS + (1.f - g) * prev_w[nm];
        const float wsn = s0 * wgp + s1 * wg0 + s2 * wgm;  // roll(-1),id,roll(+1)
        const float wsh = powf(fmaxf(wsn, 1e-12f), gam);
        ws[OFF_WSH + n] = wsh;
        tsum += wsh;
    }
    tsum = wave_sum(tsum);
    __shared__ float red[4];
    if ((t & 63) == 0) red[t >> 6] = tsum;
    __syncthreads();
    if (t == 0) ws[OFF_TPART + blockIdx.x] = red[0] + red[1] + red[2] + red[3];
}

// ---- memory update (write head hd) fused with read-address sim ----
__global__ __launch_bounds__(256) void k_update(float* __restrict__ mem,
                                                float* __restrict__ ws, int hd)
{
    const int t = threadIdx.x, lane = t & 63, wid = t >> 6;
    __shared__ float sInv;
    if (t < 64) {
        float v = wave_sum(ws[OFF_TPART + t]);
        if (t == 0) sInv = 1.f / (v + EPSC);
    }
    __syncthreads();
    const float invT = sInv;
    const int p = 4 + hd;
    const float4 k4   = *(const float4*)(ws + OFF_K + p * 256 + lane * 4);
    const float4 e4   = *(const float4*)(ws + OFF_E + hd * 256 + lane * 4);
    const float4 a4   = *(const float4*)(ws + OFF_A + hd * 256 + lane * 4);
    const float knorm = ws[OFF_SCAL + p * 8 + 0];
    const float beta  = ws[OFF_SCAL + p * 8 + 1];
    const int gw = blockIdx.x * 4 + wid;
    float m = -INFINITY, s = 0.f;
    for (int r = 0; r < 8; ++r) {
        const int n = gw * 8 + r;
        const float w = ws[OFF_WSH + n] * invT;
        float4 v = *(const float4*)(mem + (size_t)n * MSZ + lane * 4);
        v.x = v.x * (1.f - w * e4.x) + w * a4.x;
        v.y = v.y * (1.f - w * e4.y) + w * a4.y;
        v.z = v.z * (1.f - w * e4.z) + w * a4.z;
        v.w = v.w * (1.f - w * e4.w) + w * a4.w;
        *(float4*)(mem + (size_t)n * MSZ + lane * 4) = v;
        float d = v.x * k4.x + v.y * k4.y + v.z * k4.z + v.w * k4.w;
        float q = v.x * v.x + v.y * v.y + v.z * v.z + v.w * v.w;
        d = wave_sum(d); q = wave_sum(q);
        const float sim = d / (sqrtf(q) * knorm + EPSC);
        if (lane == 0) ws[OFF_SIM + n] = sim;
        online_add(beta * sim, m, s);
    }
    __shared__ float sm[4], ss2[4];
    if (lane == 0) { sm[wid] = m; ss2[wid] = s; }
    __syncthreads();
    if (t == 0) {
        float M = sm[0], S = ss2[0];
        for (int i = 1; i < 4; ++i) pair_merge(M, S, sm[i], ss2[i]);
        ws[OFF_PAIRS + blockIdx.x * 2]     = M;
        ws[OFF_PAIRS + blockIdx.x * 2 + 1] = S;
    }
}

// ---- readout (read head hd) fused with next head's write-address sim ----
__global__ __launch_bounds__(256) void k_readout(const float* __restrict__ mem,
                                                 float* __restrict__ ws, int hd, int pnext)
{
    const int t = threadIdx.x, lane = t & 63, wid = t >> 6;
    __shared__ float sInv;
    if (t < 64) {
        float v = wave_sum(ws[OFF_TPART + t]);
        if (t == 0) sInv = 1.f / (v + EPSC);
    }
    __syncthreads();
    const float invT = sInv;
    float4 k4 = make_float4(0.f, 0.f, 0.f, 0.f);
    float knorm = 1.f, beta = 0.f;
    if (pnext >= 0) {
        k4    = *(const float4*)(ws + OFF_K + pnext * 256 + lane * 4);
        knorm = ws[OFF_SCAL + pnext * 8 + 0];
        beta  = ws[OFF_SCAL + pnext * 8 + 1];
    }
    const int gw = blockIdx.x * 4 + wid;
    float m = -INFINITY, s = 0.f;
    float4 acc = make_float4(0.f, 0.f, 0.f, 0.f);
    for (int r = 0; r < 8; ++r) {
        const int n = gw * 8 + r;
        const float w = ws[OFF_WSH + n] * invT;
        const float4 v = *(const float4*)(mem + (size_t)n * MSZ + lane * 4);
        acc.x += w * v.x; acc.y += w * v.y; acc.z += w * v.z; acc.w += w * v.w;
        if (pnext >= 0) {
            float d = v.x * k4.x + v.y * k4.y + v.z * k4.z + v.w * k4.w;
            float q = v.x * v.x + v.y * v.y + v.z * v.z + v.w * v.w;
            d = wave_sum(d); q = wave_sum(q);
            const float sim = d / (sqrtf(q) * knorm + EPSC);
            if (lane == 0) ws[OFF_SIM + n] = sim;
            online_add(beta * sim, m, s);
        }
    }
    __shared__ float lacc[4][256];
    lacc[wid][lane * 4 + 0] = acc.x;
    lacc[wid][lane * 4 + 1] = acc.y;
    lacc[wid][lane * 4 + 2] = acc.z;
    lacc[wid][lane * 4 + 3] = acc.w;
    __syncthreads();
    {
        const float v = lacc[0][t] + lacc[1][t] + lacc[2][t] + lacc[3][t];
        atomicAdd(ws + OFF_READS + hd * 256 + t, v);
    }
    if (pnext >= 0) {
        __shared__ float sm[4], ss2[4];
        if (lane == 0) { sm[wid] = m; ss2[wid] = s; }
        __syncthreads();
        if (t == 0) {
            float M = sm[0], S = ss2[0];
            for (int i = 1; i < 4; ++i) pair_merge(M, S, sm[i], ss2[i]);
            ws[OFF_PAIRS + blockIdx.x * 2]     = M;
            ws[OFF_PAIRS + blockIdx.x * 2 + 1] = S;
        }
    }
}

// ---- output matvec: wave per row (2048 rows) ----
__global__ __launch_bounds__(256) void k_out(const float* __restrict__ W_out,
                                             const float* __restrict__ b_out,
                                             const float* __restrict__ ws,
                                             float* __restrict__ out)
{
    const int row  = (blockIdx.x * 256 + threadIdx.x) >> 6;
    const int lane = threadIdx.x & 63;
    const float* wr    = W_out + (size_t)row * 1024;
    const float* reads = ws + OFF_READS;
    float acc = 0.f;
#pragma unroll
    for (int j = lane * 4; j < 1024; j += 256) {
        float4 w4 = *(const float4*)(wr + j);
        float4 v4 = *(const float4*)(reads + j);
        acc += w4.x * v4.x + w4.y * v4.y + w4.z * v4.z + w4.w * v4.w;
    }
    acc = wave_sum(acc);
    if (lane == 0) out[row] = acc + b_out[row];
}

extern "C" void kernel_launch(void* const* d_in, const int* in_sizes, int n_in,
                              void* d_out, int out_size, void* d_ws, size_t ws_size,
                              hipStream_t stream) {
    (void)in_sizes; (void)n_in; (void)out_size; (void)ws_size;
    const float* x          = (const float*)d_in[0];
    const float* prev_reads = (const float*)d_in[1];
    const float* prev_h     = (const float*)d_in[2];
    const float* prev_c     = (const float*)d_in[3];
    float*       memory     = (float*)d_in[4];   // updated in place; harness restores per launch
    const float* prev_rw    = (const float*)d_in[5];
    const float* prev_ww    = (const float*)d_in[6];
    const float* W_ih       = (const float*)d_in[7];
    const float* W_hh       = (const float*)d_in[8];
    const float* b_lstm     = (const float*)d_in[9];
    const float* W_out      = (const float*)d_in[10];
    const float* b_out      = (const float*)d_in[11];
    const float* Ww         = (const float*)d_in[12];
    const float* bw         = (const float*)d_in[13];
    const float* Wr         = (const float*)d_in[14];
    const float* br         = (const float*)d_in[15];
    float* out = (float*)d_out;
    float* ws  = (float*)d_ws;

    k_init  <<<4,    256, 0, stream>>>(ws);
    k_gates <<<1024, 256, 0, stream>>>(x, prev_reads, prev_h, W_ih, W_hh, b_lstm, ws);
    k_cell  <<<4,    256, 0, stream>>>(prev_c, ws);
    k_headfc<<<1036, 256, 0, stream>>>(Ww, bw, Wr, br, ws);
    k_params<<<8,    256, 0, stream>>>(ws);
    k_sim   <<<2048, 256, 0, stream>>>(memory, ws, 0);   // head0 write-address sims
    for (int hd = 0; hd < 4; ++hd) {
        k_smax   <<<64,   256, 0, stream>>>(prev_ww + (size_t)hd * NMEM, ws, hd);
        k_update <<<2048, 256, 0, stream>>>(memory, ws, hd);
        k_smax   <<<64,   256, 0, stream>>>(prev_rw + (size_t)hd * NMEM, ws, 4 + hd);
        k_readout<<<2048, 256, 0, stream>>>(memory, ws, hd, (hd < 3) ? (hd + 1) : -1);
    }
    k_out<<<512, 256, 0, stream>>>(W_out, b_out, ws, out);
}

// Round 4
// 607.186 us; speedup vs baseline: 1.0218x; 1.0218x over previous
//
#include <hip/hip_runtime.h>
#include <cmath>

#define NMEM 65536
#define MSZ  256
#define EPSC 1e-8f

// ---- workspace layout (float offsets) ----
enum : int {
    OFF_GATES = 0,        // 4096
    OFF_CTRL  = 4096,     // 1024
    OFF_OW    = 5120,     // 4*774 = 3096
    OFF_ORR   = 8216,     // 4*262 = 1048
    OFF_K     = 9264,     // 8*256
    OFF_E     = 11312,    // 4*256
    OFF_A     = 12336,    // 4*256
    OFF_SCAL  = 13360,    // 8*8: [knorm, beta, g, s0, s1, s2, gamma, -]
    OFF_READS = 13424,    // 4*256 (atomic accumulated)
    OFF_PAIRS = 14448,    // 2048*2 online-softmax partials
    OFF_TPART = 18544,    // 256 sharpen-sum partials
    OFF_SIM   = 18800,    // 65536
    OFF_WSH   = 84336,    // 65536
    OFF_NSQ   = 149872,   // 65536 (post-update row norm^2; optional)
    WS_FLOATS = 215408
};

__device__ __forceinline__ float wave_sum(float v) {
#pragma unroll
    for (int off = 32; off > 0; off >>= 1) v += __shfl_xor(v, off);
    return v;
}
__device__ __forceinline__ float sigmoidf_(float x) { return 1.f / (1.f + expf(-x)); }
__device__ __forceinline__ float softplusf_(float x) { return (x > 20.f) ? x : log1pf(expf(x)); }
__device__ __forceinline__ void pair_merge(float& m, float& s, float m2, float s2) {
    if (m2 > m) { s = s * expf(m - m2) + s2; m = m2; }
    else        { s += s2 * expf(m2 - m); }
}
__device__ __forceinline__ float dot4(float4 a, float4 b) {
    return a.x * b.x + a.y * b.y + a.z * b.z + a.w * b.w;
}

// block-level merge of per-wave (m,s) partials -> PAIRS[blockIdx]
__device__ __forceinline__ void block_pair_out(float m, float s, float* ws,
                                               int t, int lane, int wid) {
    __shared__ float sm[4], ss2[4];
    if (lane == 0) { sm[wid] = m; ss2[wid] = s; }
    __syncthreads();
    if (t == 0) {
        float M = sm[0], S = ss2[0];
#pragma unroll
        for (int i = 1; i < 4; ++i) pair_merge(M, S, sm[i], ss2[i]);
        ws[OFF_PAIRS + blockIdx.x * 2]     = M;
        ws[OFF_PAIRS + blockIdx.x * 2 + 1] = S;
    }
}

// all-lane batched reduce of 8 values (6 stages, 8-way ILP)
#define BFLY8(arr)                                            \
    _Pragma("unroll")                                         \
    for (int off = 32; off > 0; off >>= 1) {                  \
        _Pragma("unroll")                                     \
        for (int r = 0; r < 8; ++r) arr[r] += __shfl_xor(arr[r], off); \
    }

// ---- zero the read accumulators ----
__global__ void k_init(float* __restrict__ ws) {
    int i = blockIdx.x * blockDim.x + threadIdx.x;
    if (i < 1024) ws[OFF_READS + i] = 0.f;
}

// ---- LSTM gates: one wave per output row (4096 rows) ----
__global__ __launch_bounds__(256) void k_gates(
    const float* __restrict__ x, const float* __restrict__ prev_reads,
    const float* __restrict__ prev_h, const float* __restrict__ W_ih,
    const float* __restrict__ W_hh, const float* __restrict__ b_lstm,
    float* __restrict__ ws)
{
    const int row  = (blockIdx.x * 256 + threadIdx.x) >> 6;
    const int lane = threadIdx.x & 63;
    const float* wrow = W_ih + (size_t)row * 3072;
    float acc = 0.f;
#pragma unroll
    for (int j = lane * 4; j < 3072; j += 256) {
        float4 w4 = *(const float4*)(wrow + j);
        float4 v4 = (j < 2048) ? *(const float4*)(x + j)
                               : *(const float4*)(prev_reads + (j - 2048));
        acc += dot4(w4, v4);
    }
    const float* hrow = W_hh + (size_t)row * 1024;
#pragma unroll
    for (int j = lane * 4; j < 1024; j += 256) {
        acc += dot4(*(const float4*)(hrow + j), *(const float4*)(prev_h + j));
    }
    acc = wave_sum(acc);
    if (lane == 0) ws[OFF_GATES + row] = acc + b_lstm[row];
}

// ---- LSTM cell state -> ctrl ----
__global__ void k_cell(const float* __restrict__ prev_c, float* __restrict__ ws) {
    const int j = blockIdx.x * blockDim.x + threadIdx.x;
    if (j >= 1024) return;
    const float ig = ws[OFF_GATES + j];
    const float fg = ws[OFF_GATES + 1024 + j];
    const float gg = ws[OFF_GATES + 2048 + j];
    ws[OFF_CTRL + j] = sigmoidf_(fg) * prev_c[j] + sigmoidf_(ig) * tanhf(gg);
}

// ---- head FC outputs: 3096 write rows + 1048 read rows, wave per row ----
__global__ __launch_bounds__(256) void k_headfc(
    const float* __restrict__ Ww, const float* __restrict__ bw,
    const float* __restrict__ Wr, const float* __restrict__ br,
    float* __restrict__ ws)
{
    const int gwv  = (blockIdx.x * 256 + threadIdx.x) >> 6;
    const int lane = threadIdx.x & 63;
    const float* wrow; float bias; int dst;
    if (gwv < 3096) { wrow = Ww + (size_t)gwv * 1024; bias = bw[gwv]; dst = OFF_OW + gwv; }
    else { const int rr = gwv - 3096; wrow = Wr + (size_t)rr * 1024; bias = br[rr]; dst = OFF_ORR + rr; }
    const float* ctrl = ws + OFF_CTRL;
    float acc = 0.f;
#pragma unroll
    for (int j = lane * 4; j < 1024; j += 256) {
        acc += dot4(*(const float4*)(wrow + j), *(const float4*)(ctrl + j));
    }
    acc = wave_sum(acc);
    if (lane == 0) ws[dst] = acc + bias;
}

// ---- derive per-address params: block p handles address p (0..7) ----
__global__ __launch_bounds__(256) void k_params(float* __restrict__ ws) {
    const int p = blockIdx.x, t = threadIdx.x;
    const float* o = (p < 4) ? (ws + OFF_OW + p * 774) : (ws + OFF_ORR + (p - 4) * 262);
    const float kj = tanhf(o[t]);
    ws[OFF_K + p * 256 + t] = kj;
    float ssq = wave_sum(kj * kj);
    __shared__ float red[4];
    if ((t & 63) == 0) red[t >> 6] = ssq;
    __syncthreads();
    if (t == 0) {
        float* sc = ws + OFF_SCAL + p * 8;
        sc[0] = sqrtf(red[0] + red[1] + red[2] + red[3]);
        sc[1] = softplusf_(o[256]);
        sc[2] = sigmoidf_(o[257]);
        const float a0 = o[258], a1 = o[259], a2 = o[260];
        const float mm = fmaxf(a0, fmaxf(a1, a2));
        const float e0 = expf(a0 - mm), e1 = expf(a1 - mm), e2 = expf(a2 - mm);
        const float inv = 1.f / (e0 + e1 + e2);
        sc[3] = e0 * inv; sc[4] = e1 * inv; sc[5] = e2 * inv;
        sc[6] = 1.f + softplusf_(o[261]);
    }
    if (p < 4) {
        ws[OFF_E + p * 256 + t] = sigmoidf_(o[262 + t]);
        ws[OFF_A + p * 256 + t] = tanhf(o[518 + t]);
    }
}

// ---- cosine-sim pass (head0 write address): wave handles 8 rows, batched ----
__global__ __launch_bounds__(256) void k_sim(const float* __restrict__ mem,
                                             float* __restrict__ ws, int p)
{
    const int t = threadIdx.x, lane = t & 63, wid = t >> 6;
    const int n0 = (blockIdx.x * 4 + wid) * 8;
    const float4 k4   = *(const float4*)(ws + OFF_K + p * 256 + lane * 4);
    const float knorm = ws[OFF_SCAL + p * 8 + 0];
    const float beta  = ws[OFF_SCAL + p * 8 + 1];
    float4 v[8];
#pragma unroll
    for (int r = 0; r < 8; ++r) v[r] = *(const float4*)(mem + (size_t)(n0 + r) * MSZ + lane * 4);
    float d[8], q[8];
#pragma unroll
    for (int r = 0; r < 8; ++r) { d[r] = dot4(v[r], k4); q[r] = dot4(v[r], v[r]); }
    BFLY8(d); BFLY8(q);
    float sim8[8], z8[8];
#pragma unroll
    for (int r = 0; r < 8; ++r) {
        sim8[r] = d[r] / (sqrtf(q[r]) * knorm + EPSC);
        z8[r] = beta * sim8[r];
    }
#pragma unroll
    for (int r = 0; r < 8; ++r) if (lane == r) ws[OFF_SIM + n0 + r] = sim8[r];
    float m = z8[0];
#pragma unroll
    for (int r = 1; r < 8; ++r) m = fmaxf(m, z8[r]);
    float s = 0.f;
#pragma unroll
    for (int r = 0; r < 8; ++r) s += expf(z8[r] - m);
    block_pair_out(m, s, ws, t, lane, wid);
}

// ---- softmax + interpolate + shift + sharpen: 1 element per thread ----
__global__ __launch_bounds__(256) void k_smax(const float* __restrict__ prev_w,
                                              float* __restrict__ ws, int p)
{
    const int t = threadIdx.x;
    float m = -INFINITY, s = 0.f;
    for (int i = t; i < 2048; i += 256)
        pair_merge(m, s, ws[OFF_PAIRS + 2 * i], ws[OFF_PAIRS + 2 * i + 1]);
    __shared__ float sm[256], ss[256];
    sm[t] = m; ss[t] = s;
    __syncthreads();
    for (int str = 128; str > 0; str >>= 1) {
        if (t < str) {
            float mm = sm[t], sss = ss[t];
            pair_merge(mm, sss, sm[t + str], ss[t + str]);
            sm[t] = mm; ss[t] = sss;
        }
        __syncthreads();
    }
    const float M = sm[0], invS = 1.f / ss[0];
    const float* sc = ws + OFF_SCAL + p * 8;
    const float beta = sc[1], g = sc[2], s0 = sc[3], s1 = sc[4], s2 = sc[5], gam = sc[6];
    const float* sim = ws + OFF_SIM;
    const int n  = blockIdx.x * 256 + t;
    const int np = (n + 1) & (NMEM - 1);
    const int nm = (n + NMEM - 1) & (NMEM - 1);
    const float wg0 = g * expf(beta * sim[n]  - M) * invS + (1.f - g) * prev_w[n];
    const float wgp = g * expf(beta * sim[np] - M) * invS + (1.f - g) * prev_w[np];
    const float wgm = g * expf(beta * sim[nm] - M) * invS + (1.f - g) * prev_w[nm];
    const float wsn = s0 * wgp + s1 * wg0 + s2 * wgm;  // roll(-1), id, roll(+1)
    const float wsh = powf(fmaxf(wsn, 1e-12f), gam);
    ws[OFF_WSH + n] = wsh;
    float tsum = wave_sum(wsh);
    __shared__ float red[4];
    if ((t & 63) == 0) red[t >> 6] = tsum;
    __syncthreads();
    if (t == 0) ws[OFF_TPART + blockIdx.x] = red[0] + red[1] + red[2] + red[3];
}

__device__ __forceinline__ float load_invT(const float* __restrict__ ws,
                                           int t, int lane, int wid) {
    __shared__ float red[4];
    float v = wave_sum(ws[OFF_TPART + t]);   // 256 partials, one per thread
    if (lane == 0) red[wid] = v;
    __syncthreads();
    return 1.f / (red[0] + red[1] + red[2] + red[3] + EPSC);
}

// ---- memory update (write head hd) fused with read-address sim ----
__global__ __launch_bounds__(256) void k_update(float* __restrict__ mem,
                                                float* __restrict__ ws, int hd, int store_nsq)
{
    const int t = threadIdx.x, lane = t & 63, wid = t >> 6;
    const float invT = load_invT(ws, t, lane, wid);
    const int p = 4 + hd;
    const float4 k4   = *(const float4*)(ws + OFF_K + p * 256 + lane * 4);
    const float4 e4   = *(const float4*)(ws + OFF_E + hd * 256 + lane * 4);
    const float4 a4   = *(const float4*)(ws + OFF_A + hd * 256 + lane * 4);
    const float knorm = ws[OFF_SCAL + p * 8 + 0];
    const float beta  = ws[OFF_SCAL + p * 8 + 1];
    const int n0 = (blockIdx.x * 4 + wid) * 8;
    float w8[8]; float4 v[8];
#pragma unroll
    for (int r = 0; r < 8; ++r) w8[r] = ws[OFF_WSH + n0 + r] * invT;
#pragma unroll
    for (int r = 0; r < 8; ++r) v[r] = *(const float4*)(mem + (size_t)(n0 + r) * MSZ + lane * 4);
#pragma unroll
    for (int r = 0; r < 8; ++r) {
        const float w = w8[r];
        v[r].x = v[r].x * (1.f - w * e4.x) + w * a4.x;
        v[r].y = v[r].y * (1.f - w * e4.y) + w * a4.y;
        v[r].z = v[r].z * (1.f - w * e4.z) + w * a4.z;
        v[r].w = v[r].w * (1.f - w * e4.w) + w * a4.w;
        *(float4*)(mem + (size_t)(n0 + r) * MSZ + lane * 4) = v[r];
    }
    float d[8], q[8];
#pragma unroll
    for (int r = 0; r < 8; ++r) { d[r] = dot4(v[r], k4); q[r] = dot4(v[r], v[r]); }
    BFLY8(d); BFLY8(q);
    float sim8[8], z8[8];
#pragma unroll
    for (int r = 0; r < 8; ++r) {
        sim8[r] = d[r] / (sqrtf(q[r]) * knorm + EPSC);
        z8[r] = beta * sim8[r];
    }
#pragma unroll
    for (int r = 0; r < 8; ++r) if (lane == r) ws[OFF_SIM + n0 + r] = sim8[r];
    if (store_nsq) {
#pragma unroll
        for (int r = 0; r < 8; ++r) if (lane == r) ws[OFF_NSQ + n0 + r] = q[r];
    }
    float m = z8[0];
#pragma unroll
    for (int r = 1; r < 8; ++r) m = fmaxf(m, z8[r]);
    float s = 0.f;
#pragma unroll
    for (int r = 0; r < 8; ++r) s += expf(z8[r] - m);
    block_pair_out(m, s, ws, t, lane, wid);
}

// ---- readout (read head hd) fused with next head's write-address sim ----
__global__ __launch_bounds__(256) void k_readout(const float* __restrict__ mem,
                                                 float* __restrict__ ws, int hd,
                                                 int pnext, int use_nsq)
{
    const int t = threadIdx.x, lane = t & 63, wid = t >> 6;
    const float invT = load_invT(ws, t, lane, wid);
    float4 k4 = make_float4(0.f, 0.f, 0.f, 0.f);
    float knorm = 1.f, beta = 0.f;
    if (pnext >= 0) {
        k4    = *(const float4*)(ws + OFF_K + pnext * 256 + lane * 4);
        knorm = ws[OFF_SCAL + pnext * 8 + 0];
        beta  = ws[OFF_SCAL + pnext * 8 + 1];
    }
    const int n0 = (blockIdx.x * 4 + wid) * 8;
    float w8[8]; float4 v[8];
#pragma unroll
    for (int r = 0; r < 8; ++r) w8[r] = ws[OFF_WSH + n0 + r] * invT;
#pragma unroll
    for (int r = 0; r < 8; ++r) v[r] = *(const float4*)(mem + (size_t)(n0 + r) * MSZ + lane * 4);
    float4 acc = make_float4(0.f, 0.f, 0.f, 0.f);
#pragma unroll
    for (int r = 0; r < 8; ++r) {
        acc.x += w8[r] * v[r].x; acc.y += w8[r] * v[r].y;
        acc.z += w8[r] * v[r].z; acc.w += w8[r] * v[r].w;
    }
    float m = -INFINITY, s = 0.f;
    if (pnext >= 0) {
        float d[8], q[8];
#pragma unroll
        for (int r = 0; r < 8; ++r) d[r] = dot4(v[r], k4);
        BFLY8(d);
        if (use_nsq) {
#pragma unroll
            for (int r = 0; r < 8; ++r) q[r] = ws[OFF_NSQ + n0 + r];
        } else {
#pragma unroll
            for (int r = 0; r < 8; ++r) q[r] = dot4(v[r], v[r]);
            BFLY8(q);
        }
        float sim8[8], z8[8];
#pragma unroll
        for (int r = 0; r < 8; ++r) {
            sim8[r] = d[r] / (sqrtf(q[r]) * knorm + EPSC);
            z8[r] = beta * sim8[r];
        }
#pragma unroll
        for (int r = 0; r < 8; ++r) if (lane == r) ws[OFF_SIM + n0 + r] = sim8[r];
        m = z8[0];
#pragma unroll
        for (int r = 1; r < 8; ++r) m = fmaxf(m, z8[r]);
#pragma unroll
        for (int r = 0; r < 8; ++r) s += expf(z8[r] - m);
    }
    __shared__ float lacc[4][256];
    lacc[wid][lane * 4 + 0] = acc.x;
    lacc[wid][lane * 4 + 1] = acc.y;
    lacc[wid][lane * 4 + 2] = acc.z;
    lacc[wid][lane * 4 + 3] = acc.w;
    __syncthreads();
    {
        const float vv = lacc[0][t] + lacc[1][t] + lacc[2][t] + lacc[3][t];
        atomicAdd(ws + OFF_READS + hd * 256 + t, vv);
    }
    if (pnext >= 0) block_pair_out(m, s, ws, t, lane, wid);
}

// ---- output matvec: wave per row (2048 rows) ----
__global__ __launch_bounds__(256) void k_out(const float* __restrict__ W_out,
                                             const float* __restrict__ b_out,
                                             const float* __restrict__ ws,
                                             float* __restrict__ out)
{
    const int row  = (blockIdx.x * 256 + threadIdx.x) >> 6;
    const int lane = threadIdx.x & 63;
    const float* wr    = W_out + (size_t)row * 1024;
    const float* reads = ws + OFF_READS;
    float acc = 0.f;
#pragma unroll
    for (int j = lane * 4; j < 1024; j += 256) {
        acc += dot4(*(const float4*)(wr + j), *(const float4*)(reads + j));
    }
    acc = wave_sum(acc);
    if (lane == 0) out[row] = acc + b_out[row];
}

extern "C" void kernel_launch(void* const* d_in, const int* in_sizes, int n_in,
                              void* d_out, int out_size, void* d_ws, size_t ws_size,
                              hipStream_t stream) {
    (void)in_sizes; (void)n_in; (void)out_size;
    const float* x          = (const float*)d_in[0];
    const float* prev_reads = (const float*)d_in[1];
    const float* prev_h     = (const float*)d_in[2];
    const float* prev_c     = (const float*)d_in[3];
    float*       memory     = (float*)d_in[4];   // updated in place; harness restores per launch
    const float* prev_rw    = (const float*)d_in[5];
    const float* prev_ww    = (const float*)d_in[6];
    const float* W_ih       = (const float*)d_in[7];
    const float* W_hh       = (const float*)d_in[8];
    const float* b_lstm     = (const float*)d_in[9];
    const float* W_out      = (const float*)d_in[10];
    const float* b_out      = (const float*)d_in[11];
    const float* Ww         = (const float*)d_in[12];
    const float* bw         = (const float*)d_in[13];
    const float* Wr         = (const float*)d_in[14];
    const float* br         = (const float*)d_in[15];
    float* out = (float*)d_out;
    float* ws  = (float*)d_ws;
    const int use_nsq = (ws_size >= (size_t)WS_FLOATS * sizeof(float)) ? 1 : 0;

    k_init  <<<4,    256, 0, stream>>>(ws);
    k_gates <<<1024, 256, 0, stream>>>(x, prev_reads, prev_h, W_ih, W_hh, b_lstm, ws);
    k_cell  <<<4,    256, 0, stream>>>(prev_c, ws);
    k_headfc<<<1036, 256, 0, stream>>>(Ww, bw, Wr, br, ws);
    k_params<<<8,    256, 0, stream>>>(ws);
    k_sim   <<<2048, 256, 0, stream>>>(memory, ws, 0);
    for (int hd = 0; hd < 4; ++hd) {
        k_smax   <<<256,  256, 0, stream>>>(prev_ww + (size_t)hd * NMEM, ws, hd);
        k_update <<<2048, 256, 0, stream>>>(memory, ws, hd, use_nsq);
        k_smax   <<<256,  256, 0, stream>>>(prev_rw + (size_t)hd * NMEM, ws, 4 + hd);
        k_readout<<<2048, 256, 0, stream>>>(memory, ws, hd, (hd < 3) ? (hd + 1) : -1, use_nsq);
    }
    k_out<<<512, 256, 0, stream>>>(W_out, b_out, ws, out);
}

// Round 5
// 479.689 us; speedup vs baseline: 1.2934x; 1.2658x over previous
//
#include <hip/hip_runtime.h>
#include <cmath>

#define NMEM 65536
#define MSZ  256
#define EPSC 1e-8f
#define GRID_BIG 512          // big-pass blocks; 128 rows each, 32/wave, 4 batches of 8

// ---- workspace layout (float offsets) ----
enum : int {
    OFF_GATES = 0,        // 4096
    OFF_CTRL  = 4096,     // 1024
    OFF_OW    = 5120,     // 4*774 = 3096
    OFF_ORR   = 8216,     // 4*262 = 1048
    OFF_K     = 9264,     // 8*256
    OFF_E     = 11312,    // 4*256
    OFF_A     = 12336,    // 4*256
    OFF_SCAL  = 13360,    // 8*8: [knorm, beta, g, s0, s1, s2, gamma, -]
    OFF_READS = 13424,    // 4*256 (atomic accumulated)
    OFF_PAIRS = 14448,    // 512*2 online-softmax partials
    OFF_TPART = 15472,    // 256 sharpen-sum partials
    OFF_SIM   = 15728,    // 65536
    OFF_WSH   = 81264,    // 65536
    OFF_NSQ   = 146800,   // 65536 (post-update row norm^2; optional)
    WS_FLOATS = 212336
};

__device__ __forceinline__ float wave_sum(float v) {
#pragma unroll
    for (int off = 32; off > 0; off >>= 1) v += __shfl_xor(v, off);
    return v;
}
__device__ __forceinline__ float sigmoidf_(float x) { return 1.f / (1.f + expf(-x)); }
__device__ __forceinline__ float softplusf_(float x) { return (x > 20.f) ? x : log1pf(expf(x)); }
__device__ __forceinline__ void pair_merge(float& m, float& s, float m2, float s2) {
    if (m2 > m) { s = s * expf(m - m2) + s2; m = m2; }
    else        { s += s2 * expf(m2 - m); }
}
__device__ __forceinline__ float dot4(float4 a, float4 b) {
    return a.x * b.x + a.y * b.y + a.z * b.z + a.w * b.w;
}

// block-level merge of per-wave (m,s) partials -> PAIRS[blockIdx]
__device__ __forceinline__ void block_pair_out(float m, float s, float* ws,
                                               int t, int lane, int wid) {
    __shared__ float sm[4], ss2[4];
    if (lane == 0) { sm[wid] = m; ss2[wid] = s; }
    __syncthreads();
    if (t == 0) {
        float M = sm[0], S = ss2[0];
#pragma unroll
        for (int i = 1; i < 4; ++i) pair_merge(M, S, sm[i], ss2[i]);
        ws[OFF_PAIRS + blockIdx.x * 2]     = M;
        ws[OFF_PAIRS + blockIdx.x * 2 + 1] = S;
    }
}

// all-lane batched reduce of 8 values (6 stages, 8-way ILP)
#define BFLY8(arr)                                            \
    _Pragma("unroll")                                         \
    for (int off = 32; off > 0; off >>= 1) {                  \
        _Pragma("unroll")                                     \
        for (int r = 0; r < 8; ++r) arr[r] += __shfl_xor(arr[r], off); \
    }

// ---- LSTM gates: one wave per output row (4096 rows) ----
__global__ __launch_bounds__(256) void k_gates(
    const float* __restrict__ x, const float* __restrict__ prev_reads,
    const float* __restrict__ prev_h, const float* __restrict__ W_ih,
    const float* __restrict__ W_hh, const float* __restrict__ b_lstm,
    float* __restrict__ ws)
{
    const int row  = (blockIdx.x * 256 + threadIdx.x) >> 6;
    const int lane = threadIdx.x & 63;
    const float* wrow = W_ih + (size_t)row * 3072;
    float acc = 0.f;
#pragma unroll
    for (int j = lane * 4; j < 3072; j += 256) {
        float4 w4 = *(const float4*)(wrow + j);
        float4 v4 = (j < 2048) ? *(const float4*)(x + j)
                               : *(const float4*)(prev_reads + (j - 2048));
        acc += dot4(w4, v4);
    }
    const float* hrow = W_hh + (size_t)row * 1024;
#pragma unroll
    for (int j = lane * 4; j < 1024; j += 256) {
        acc += dot4(*(const float4*)(hrow + j), *(const float4*)(prev_h + j));
    }
    acc = wave_sum(acc);
    if (lane == 0) ws[OFF_GATES + row] = acc + b_lstm[row];
}

// ---- LSTM cell state -> ctrl ----
__global__ void k_cell(const float* __restrict__ prev_c, float* __restrict__ ws) {
    const int j = blockIdx.x * blockDim.x + threadIdx.x;
    if (j >= 1024) return;
    const float ig = ws[OFF_GATES + j];
    const float fg = ws[OFF_GATES + 1024 + j];
    const float gg = ws[OFF_GATES + 2048 + j];
    ws[OFF_CTRL + j] = sigmoidf_(fg) * prev_c[j] + sigmoidf_(ig) * tanhf(gg);
}

// ---- head FC outputs: 3096 write rows + 1048 read rows, wave per row ----
__global__ __launch_bounds__(256) void k_headfc(
    const float* __restrict__ Ww, const float* __restrict__ bw,
    const float* __restrict__ Wr, const float* __restrict__ br,
    float* __restrict__ ws)
{
    const int gwv  = (blockIdx.x * 256 + threadIdx.x) >> 6;
    const int lane = threadIdx.x & 63;
    const float* wrow; float bias; int dst;
    if (gwv < 3096) { wrow = Ww + (size_t)gwv * 1024; bias = bw[gwv]; dst = OFF_OW + gwv; }
    else { const int rr = gwv - 3096; wrow = Wr + (size_t)rr * 1024; bias = br[rr]; dst = OFF_ORR + rr; }
    const float* ctrl = ws + OFF_CTRL;
    float acc = 0.f;
#pragma unroll
    for (int j = lane * 4; j < 1024; j += 256) {
        acc += dot4(*(const float4*)(wrow + j), *(const float4*)(ctrl + j));
    }
    acc = wave_sum(acc);
    if (lane == 0) ws[dst] = acc + bias;
}

// ---- per-address params (+ zero READS): block p handles address p (0..7) ----
__global__ __launch_bounds__(256) void k_params(float* __restrict__ ws) {
    const int p = blockIdx.x, t = threadIdx.x;
    const float* o = (p < 4) ? (ws + OFF_OW + p * 774) : (ws + OFF_ORR + (p - 4) * 262);
    const float kj = tanhf(o[t]);
    ws[OFF_K + p * 256 + t] = kj;
    float ssq = wave_sum(kj * kj);
    __shared__ float red[4];
    if ((t & 63) == 0) red[t >> 6] = ssq;
    __syncthreads();
    if (t == 0) {
        float* sc = ws + OFF_SCAL + p * 8;
        sc[0] = sqrtf(red[0] + red[1] + red[2] + red[3]);
        sc[1] = softplusf_(o[256]);
        sc[2] = sigmoidf_(o[257]);
        const float a0 = o[258], a1 = o[259], a2 = o[260];
        const float mm = fmaxf(a0, fmaxf(a1, a2));
        const float e0 = expf(a0 - mm), e1 = expf(a1 - mm), e2 = expf(a2 - mm);
        const float inv = 1.f / (e0 + e1 + e2);
        sc[3] = e0 * inv; sc[4] = e1 * inv; sc[5] = e2 * inv;
        sc[6] = 1.f + softplusf_(o[261]);
    }
    if (p < 4) {
        ws[OFF_E + p * 256 + t] = sigmoidf_(o[262 + t]);
        ws[OFF_A + p * 256 + t] = tanhf(o[518 + t]);
        ws[OFF_READS + p * 256 + t] = 0.f;   // init accumulators (ws is poisoned)
    }
}

// ---- cosine-sim pass (head0 write address): 512 blocks, 32 rows/wave ----
__global__ __launch_bounds__(256) void k_sim(const float* __restrict__ mem,
                                             float* __restrict__ ws, int p)
{
    const int t = threadIdx.x, lane = t & 63, wid = t >> 6;
    const float4 k4   = *(const float4*)(ws + OFF_K + p * 256 + lane * 4);
    const float knorm = ws[OFF_SCAL + p * 8 + 0];
    const float beta  = ws[OFF_SCAL + p * 8 + 1];
    float m = -INFINITY, s = 0.f;
#pragma unroll
    for (int b = 0; b < 4; ++b) {
        const int n0 = blockIdx.x * 128 + wid * 32 + b * 8;
        float4 v[8];
#pragma unroll
        for (int r = 0; r < 8; ++r) v[r] = *(const float4*)(mem + (size_t)(n0 + r) * MSZ + lane * 4);
        float d[8], q[8];
#pragma unroll
        for (int r = 0; r < 8; ++r) { d[r] = dot4(v[r], k4); q[r] = dot4(v[r], v[r]); }
        BFLY8(d); BFLY8(q);
        float z8[8];
#pragma unroll
        for (int r = 0; r < 8; ++r) {
            const float sim = d[r] / (sqrtf(q[r]) * knorm + EPSC);
            if (lane == r) ws[OFF_SIM + n0 + r] = sim;
            z8[r] = beta * sim;
        }
        float mb = z8[0];
#pragma unroll
        for (int r = 1; r < 8; ++r) mb = fmaxf(mb, z8[r]);
        float sb = 0.f;
#pragma unroll
        for (int r = 0; r < 8; ++r) sb += expf(z8[r] - mb);
        pair_merge(m, s, mb, sb);
    }
    block_pair_out(m, s, ws, t, lane, wid);
}

// ---- softmax + interpolate + shift + sharpen: 1 element per thread ----
__global__ __launch_bounds__(256) void k_smax(const float* __restrict__ prev_w,
                                              float* __restrict__ ws, int p)
{
    const int t = threadIdx.x;
    float m = ws[OFF_PAIRS + 2 * t], s = ws[OFF_PAIRS + 2 * t + 1];
    pair_merge(m, s, ws[OFF_PAIRS + 2 * (t + 256)], ws[OFF_PAIRS + 2 * (t + 256) + 1]);
    __shared__ float sm[256], ss[256];
    sm[t] = m; ss[t] = s;
    __syncthreads();
    for (int str = 128; str > 0; str >>= 1) {
        if (t < str) {
            float mm = sm[t], sss = ss[t];
            pair_merge(mm, sss, sm[t + str], ss[t + str]);
            sm[t] = mm; ss[t] = sss;
        }
        __syncthreads();
    }
    const float M = sm[0], invS = 1.f / ss[0];
    const float* sc = ws + OFF_SCAL + p * 8;
    const float beta = sc[1], g = sc[2], s0 = sc[3], s1 = sc[4], s2 = sc[5], gam = sc[6];
    const float* sim = ws + OFF_SIM;
    const int n  = blockIdx.x * 256 + t;
    const int np = (n + 1) & (NMEM - 1);
    const int nm = (n + NMEM - 1) & (NMEM - 1);
    const float wg0 = g * expf(beta * sim[n]  - M) * invS + (1.f - g) * prev_w[n];
    const float wgp = g * expf(beta * sim[np] - M) * invS + (1.f - g) * prev_w[np];
    const float wgm = g * expf(beta * sim[nm] - M) * invS + (1.f - g) * prev_w[nm];
    const float wsn = s0 * wgp + s1 * wg0 + s2 * wgm;  // roll(-1), id, roll(+1)
    const float wsh = powf(fmaxf(wsn, 1e-12f), gam);
    ws[OFF_WSH + n] = wsh;
    float tsum = wave_sum(wsh);
    __shared__ float red[4];
    if ((t & 63) == 0) red[t >> 6] = tsum;
    __syncthreads();
    if (t == 0) ws[OFF_TPART + blockIdx.x] = red[0] + red[1] + red[2] + red[3];
}

__device__ __forceinline__ float load_invT(const float* __restrict__ ws,
                                           int t, int lane, int wid) {
    __shared__ float red[4];
    float v = wave_sum(ws[OFF_TPART + t]);   // 256 partials, one per thread
    if (lane == 0) red[wid] = v;
    __syncthreads();
    return 1.f / (red[0] + red[1] + red[2] + red[3] + EPSC);
}

// ---- memory update (write head hd) fused with read-address sim ----
__global__ __launch_bounds__(256) void k_update(float* __restrict__ mem,
                                                float* __restrict__ ws, int hd, int store_nsq)
{
    const int t = threadIdx.x, lane = t & 63, wid = t >> 6;
    const float invT = load_invT(ws, t, lane, wid);
    const int p = 4 + hd;
    const float4 k4   = *(const float4*)(ws + OFF_K + p * 256 + lane * 4);
    const float4 e4   = *(const float4*)(ws + OFF_E + hd * 256 + lane * 4);
    const float4 a4   = *(const float4*)(ws + OFF_A + hd * 256 + lane * 4);
    const float knorm = ws[OFF_SCAL + p * 8 + 0];
    const float beta  = ws[OFF_SCAL + p * 8 + 1];
    float m = -INFINITY, s = 0.f;
#pragma unroll
    for (int b = 0; b < 4; ++b) {
        const int n0 = blockIdx.x * 128 + wid * 32 + b * 8;
        float w8[8]; float4 v[8];
#pragma unroll
        for (int r = 0; r < 8; ++r) w8[r] = ws[OFF_WSH + n0 + r] * invT;
#pragma unroll
        for (int r = 0; r < 8; ++r) v[r] = *(const float4*)(mem + (size_t)(n0 + r) * MSZ + lane * 4);
#pragma unroll
        for (int r = 0; r < 8; ++r) {
            const float w = w8[r];
            v[r].x = v[r].x * (1.f - w * e4.x) + w * a4.x;
            v[r].y = v[r].y * (1.f - w * e4.y) + w * a4.y;
            v[r].z = v[r].z * (1.f - w * e4.z) + w * a4.z;
            v[r].w = v[r].w * (1.f - w * e4.w) + w * a4.w;
            *(float4*)(mem + (size_t)(n0 + r) * MSZ + lane * 4) = v[r];
        }
        float d[8], q[8];
#pragma unroll
        for (int r = 0; r < 8; ++r) { d[r] = dot4(v[r], k4); q[r] = dot4(v[r], v[r]); }
        BFLY8(d); BFLY8(q);
        float z8[8];
#pragma unroll
        for (int r = 0; r < 8; ++r) {
            const float sim = d[r] / (sqrtf(q[r]) * knorm + EPSC);
            if (lane == r) {
                ws[OFF_SIM + n0 + r] = sim;
                if (store_nsq) ws[OFF_NSQ + n0 + r] = q[r];
            }
            z8[r] = beta * sim;
        }
        float mb = z8[0];
#pragma unroll
        for (int r = 1; r < 8; ++r) mb = fmaxf(mb, z8[r]);
        float sb = 0.f;
#pragma unroll
        for (int r = 0; r < 8; ++r) sb += expf(z8[r] - mb);
        pair_merge(m, s, mb, sb);
    }
    block_pair_out(m, s, ws, t, lane, wid);
}

// ---- readout (read head hd) fused with next head's write-address sim ----
__global__ __launch_bounds__(256) void k_readout(const float* __restrict__ mem,
                                                 float* __restrict__ ws, int hd,
                                                 int pnext, int use_nsq)
{
    const int t = threadIdx.x, lane = t & 63, wid = t >> 6;
    const float invT = load_invT(ws, t, lane, wid);
    float4 k4 = make_float4(0.f, 0.f, 0.f, 0.f);
    float knorm = 1.f, beta = 0.f;
    if (pnext >= 0) {
        k4    = *(const float4*)(ws + OFF_K + pnext * 256 + lane * 4);
        knorm = ws[OFF_SCAL + pnext * 8 + 0];
        beta  = ws[OFF_SCAL + pnext * 8 + 1];
    }
    float m = -INFINITY, s = 0.f;
    float4 acc = make_float4(0.f, 0.f, 0.f, 0.f);
#pragma unroll
    for (int b = 0; b < 4; ++b) {
        const int n0 = blockIdx.x * 128 + wid * 32 + b * 8;
        float w8[8]; float4 v[8];
#pragma unroll
        for (int r = 0; r < 8; ++r) w8[r] = ws[OFF_WSH + n0 + r] * invT;
#pragma unroll
        for (int r = 0; r < 8; ++r) v[r] = *(const float4*)(mem + (size_t)(n0 + r) * MSZ + lane * 4);
#pragma unroll
        for (int r = 0; r < 8; ++r) {
            acc.x += w8[r] * v[r].x; acc.y += w8[r] * v[r].y;
            acc.z += w8[r] * v[r].z; acc.w += w8[r] * v[r].w;
        }
        if (pnext >= 0) {
            float d[8], q[8];
#pragma unroll
            for (int r = 0; r < 8; ++r) d[r] = dot4(v[r], k4);
            BFLY8(d);
            if (use_nsq) {
#pragma unroll
                for (int r = 0; r < 8; ++r) q[r] = ws[OFF_NSQ + n0 + r];
            } else {
#pragma unroll
                for (int r = 0; r < 8; ++r) q[r] = dot4(v[r], v[r]);
                BFLY8(q);
            }
            float z8[8];
#pragma unroll
            for (int r = 0; r < 8; ++r) {
                const float sim = d[r] / (sqrtf(q[r]) * knorm + EPSC);
                if (lane == r) ws[OFF_SIM + n0 + r] = sim;
                z8[r] = beta * sim;
            }
            float mb = z8[0];
#pragma unroll
            for (int r = 1; r < 8; ++r) mb = fmaxf(mb, z8[r]);
            float sb = 0.f;
#pragma unroll
            for (int r = 0; r < 8; ++r) sb += expf(z8[r] - mb);
            pair_merge(m, s, mb, sb);
        }
    }
    __shared__ float lacc[4][256];
    lacc[wid][lane * 4 + 0] = acc.x;
    lacc[wid][lane * 4 + 1] = acc.y;
    lacc[wid][lane * 4 + 2] = acc.z;
    lacc[wid][lane * 4 + 3] = acc.w;
    __syncthreads();
    {
        const float vv = lacc[0][t] + lacc[1][t] + lacc[2][t] + lacc[3][t];
        atomicAdd(ws + OFF_READS + hd * 256 + t, vv);   // 512 atomics/address total
    }
    if (pnext >= 0) block_pair_out(m, s, ws, t, lane, wid);
}

// ---- output matvec: wave per row (2048 rows) ----
__global__ __launch_bounds__(256) void k_out(const float* __restrict__ W_out,
                                             const float* __restrict__ b_out,
                                             const float* __restrict__ ws,
                                             float* __restrict__ out)
{
    const int row  = (blockIdx.x * 256 + threadIdx.x) >> 6;
    const int lane = threadIdx.x & 63;
    const float* wr    = W_out + (size_t)row * 1024;
    const float* reads = ws + OFF_READS;
    float acc = 0.f;
#pragma unroll
    for (int j = lane * 4; j < 1024; j += 256) {
        acc += dot4(*(const float4*)(wr + j), *(const float4*)(reads + j));
    }
    acc = wave_sum(acc);
    if (lane == 0) out[row] = acc + b_out[row];
}

extern "C" void kernel_launch(void* const* d_in, const int* in_sizes, int n_in,
                              void* d_out, int out_size, void* d_ws, size_t ws_size,
                              hipStream_t stream) {
    (void)in_sizes; (void)n_in; (void)out_size;
    const float* x          = (const float*)d_in[0];
    const float* prev_reads = (const float*)d_in[1];
    const float* prev_h     = (const float*)d_in[2];
    const float* prev_c     = (const float*)d_in[3];
    float*       memory     = (float*)d_in[4];   // updated in place; harness restores per launch
    const float* prev_rw    = (const float*)d_in[5];
    const float* prev_ww    = (const float*)d_in[6];
    const float* W_ih       = (const float*)d_in[7];
    const float* W_hh       = (const float*)d_in[8];
    const float* b_lstm     = (const float*)d_in[9];
    const float* W_out      = (const float*)d_in[10];
    const float* b_out      = (const float*)d_in[11];
    const float* Ww         = (const float*)d_in[12];
    const float* bw         = (const float*)d_in[13];
    const float* Wr         = (const float*)d_in[14];
    const float* br         = (const float*)d_in[15];
    float* out = (float*)d_out;
    float* ws  = (float*)d_ws;
    const int use_nsq = (ws_size >= (size_t)WS_FLOATS * sizeof(float)) ? 1 : 0;

    k_gates <<<1024, 256, 0, stream>>>(x, prev_reads, prev_h, W_ih, W_hh, b_lstm, ws);
    k_cell  <<<4,    256, 0, stream>>>(prev_c, ws);
    k_headfc<<<1036, 256, 0, stream>>>(Ww, bw, Wr, br, ws);
    k_params<<<8,    256, 0, stream>>>(ws);
    k_sim   <<<GRID_BIG, 256, 0, stream>>>(memory, ws, 0);
    for (int hd = 0; hd < 4; ++hd) {
        k_smax   <<<256,      256, 0, stream>>>(prev_ww + (size_t)hd * NMEM, ws, hd);
        k_update <<<GRID_BIG, 256, 0, stream>>>(memory, ws, hd, use_nsq);
        k_smax   <<<256,      256, 0, stream>>>(prev_rw + (size_t)hd * NMEM, ws, 4 + hd);
        k_readout<<<GRID_BIG, 256, 0, stream>>>(memory, ws, hd, (hd < 3) ? (hd + 1) : -1, use_nsq);
    }
    k_out<<<512, 256, 0, stream>>>(W_out, b_out, ws, out);
}